// Round 2
// baseline (187.537 us; speedup 1.0000x reference)
//
#include <hip/hip_runtime.h>

// Problem constants
constexpr int Bb  = 16;
constexpr int CDD = 10;
constexpr int Lc  = 64;
constexpr int T   = 128;
constexpr int H   = 768;
constexpr int NH  = 12;
constexpr int DH  = 64;    // H/NH
constexpr int S   = 768;   // CDD*Lc + T
constexpr int SQ  = 640;   // CDD*Lc
constexpr int MROWS = Bb * S;  // 12288

typedef __attribute__((ext_vector_type(8))) short bf16x8;
typedef __attribute__((ext_vector_type(4))) short bf16x4;
typedef __attribute__((ext_vector_type(4))) float f32x4;

__device__ inline unsigned short f2bf(float f) {
  unsigned u = __float_as_uint(f);
  u += 0x7fff + ((u >> 16) & 1);   // RNE
  return (unsigned short)(u >> 16);
}
__device__ inline float bf2f(unsigned short h) {
  return __uint_as_float(((unsigned)h) << 16);
}

__device__ inline void gld_lds16(const void* g, void* l) {
  __builtin_amdgcn_global_load_lds(
      (const __attribute__((address_space(1))) void*)g,
      (__attribute__((address_space(3))) void*)l, 16, 0, 0);
}

__device__ inline bf16x8 ld_b64x2(const unsigned short* p) {
  union { bf16x8 v; bf16x4 h[2]; } u;
  u.h[0] = *(const bf16x4*)p;
  u.h[1] = *(const bf16x4*)(p + 4);
  return u.v;
}

// ---------------- fp32 -> bf16 convert (X + 3 weights, one launch) ------------
constexpr int NX4 = MROWS * H / 4;   // 2359296 float4s
constexpr int NW4 = H * H / 4;       // 147456 float4s
__global__ void convert_all(const float* __restrict__ X,
                            const float* __restrict__ Wq,
                            const float* __restrict__ Wk,
                            const float* __restrict__ Wv,
                            unsigned short* __restrict__ Xb,
                            unsigned short* __restrict__ Wb) {
  int i = blockIdx.x * blockDim.x + threadIdx.x;
  const int stride = gridDim.x * blockDim.x;
  const int total = NX4 + 3 * NW4;
  for (; i < total; i += stride) {
    const float* src;
    unsigned short* dst;
    int off;
    if (i < NX4) {
      src = X; dst = Xb; off = i;
    } else {
      int k = i - NX4;
      int w = k / NW4;
      off = k - w * NW4;
      src = (w == 0) ? Wq : (w == 1) ? Wk : Wv;
      dst = Wb + (size_t)w * H * H;
    }
    float4 v = ((const float4*)src)[off];
    ushort4 o;
    o.x = f2bf(v.x); o.y = f2bf(v.y); o.z = f2bf(v.z); o.w = f2bf(v.w);
    ((ushort4*)dst)[off] = o;
  }
}

// ---------------- QKV projection GEMM: Y = X * W^T + bias ----------------
// M=12288, N=2304 (z merged into grid.y), K=768.
// 256x256 tile, BK=64 (12 K-tiles), 512 threads = 8 waves.
// Interleaved wave ownership: wave wr owns rows [wr*64,+64) u [128+wr*64,+64),
// wave wc owns cols [wc*32,+32) u [128+wc*32,+32)  ->  each C-quadrant (mh,nh)
// is computed by ALL waves, reading exactly half-tiles {A(mh), B(nh)}.
// Schedule per K-tile (4 phases = quadrants Q00,Q01,Q10,Q11):
//   phase: { ds_read frags | stage 1 half-tile of tile t+1 (2 gld_lds) |
//            counted s_waitcnt vmcnt(4) | s_barrier | 16 MFMA (setprio) | s_barrier }
// Staging order Alo,Blo,Bhi,Ahi; gates at phases 0,1,3 retire exactly the
// half-tiles the NEXT phase reads, always leaving 4 loads in flight (T4).
// Raw s_barrier (no vmcnt drain) -- __syncthreads would drain vmcnt(0).
__launch_bounds__(512, 2)
__global__ void qkv_gemm(const unsigned short* __restrict__ Xb,
                         const unsigned short* __restrict__ Wb,
                         const float* __restrict__ bq, const float* __restrict__ bk,
                         const float* __restrict__ bv,
                         unsigned short* __restrict__ Qb, unsigned short* __restrict__ Kb,
                         unsigned short* __restrict__ Vb,
                         float* __restrict__ part,
                         float* __restrict__ out) {
  const int z  = blockIdx.y / 3;
  const int j0 = (blockIdx.y % 3) * 256;
  const int i0 = blockIdx.x * 256;
  const int xb3 = blockIdx.x % 3;        // which 256-row third of the batch
  const unsigned short* W = Wb + (size_t)z * H * H;
  const float* bias = (z == 0) ? bq : (z == 1) ? bk : bv;
  unsigned short* Y = (z == 0) ? Qb : (z == 1) ? Kb : Vb;

  const int tid = threadIdx.x;
  const int wave = tid >> 6, lane = tid & 63;
  const int wr = wave >> 2, wc = wave & 3;      // wr 0..1 (M), wc 0..3 (N)
  const int col = lane & 15, quad = lane >> 4;

  // Q tail rows (640..767 of each batch) = mh==1 quadrants of xb3==2 tiles:
  // never consumed by attention -> skip those quadrants (block-uniform).
  const bool skipHi = (z == 0) && (xb3 == 2);

  // double-buffered A/B tiles, 256 rows x 64 cols bf16 each (128 KiB total)
  __shared__ unsigned short As0[256 * 64];
  __shared__ unsigned short As1[256 * 64];
  __shared__ unsigned short Bs0[256 * 64];
  __shared__ unsigned short Bs1[256 * 64];

  f32x4 acc[8][4];
#pragma unroll
  for (int i = 0; i < 8; i++)
#pragma unroll
    for (int j = 0; j < 4; j++) acc[i][j] = (f32x4){0.f, 0.f, 0.f, 0.f};

  bf16x8 a[4][2];      // A frags of current mh (mt, kh)
  bf16x8 b[2][2][2];   // B frags (nh, nf, kh) -- cached across mh phases

#define STAGE_HALF(src, dst, rowbase, k0, hf)                                   \
  do {                                                                          \
    _Pragma("unroll") for (int u = 0; u < 2; u++) {                             \
      const int s_ = tid + 512 * u;                                             \
      const int r_ = (s_ >> 3) + (hf) * 128;                                    \
      const int c_ = s_ & 7;                                                    \
      gld_lds16((src) + (size_t)((rowbase) + r_) * H + (k0) + ((c_ ^ (r_ & 7)) * 8), \
                &(dst)[(r_ * 8 + c_) * 8]);                                     \
    }                                                                           \
  } while (0)

#define READ_A(mh_)                                                             \
  do {                                                                          \
    _Pragma("unroll") for (int mt = 0; mt < 4; mt++) {                          \
      const int r_ = (mh_) * 128 + wr * 64 + mt * 16 + col;                     \
      _Pragma("unroll") for (int kh = 0; kh < 2; kh++)                          \
        a[mt][kh] = *(const bf16x8*)&Ar[r_ * 64 + (((kh * 4 + quad) ^ (r_ & 7)) * 8)]; \
    }                                                                           \
  } while (0)

#define READ_B(nh_)                                                             \
  do {                                                                          \
    _Pragma("unroll") for (int nf = 0; nf < 2; nf++) {                          \
      const int r_ = (nh_) * 128 + wc * 32 + nf * 16 + col;                     \
      _Pragma("unroll") for (int kh = 0; kh < 2; kh++)                          \
        b[nh_][nf][kh] = *(const bf16x8*)&Br[r_ * 64 + (((kh * 4 + quad) ^ (r_ & 7)) * 8)]; \
    }                                                                           \
  } while (0)

#define MFMA16(mh_, nh_)                                                        \
  do {                                                                          \
    __builtin_amdgcn_s_setprio(1);                                              \
    _Pragma("unroll") for (int mt = 0; mt < 4; mt++)                            \
      _Pragma("unroll") for (int nf = 0; nf < 2; nf++)                          \
        _Pragma("unroll") for (int kh = 0; kh < 2; kh++)                        \
          acc[(mh_) * 4 + mt][(nh_) * 2 + nf] =                                 \
              __builtin_amdgcn_mfma_f32_16x16x32_bf16(                          \
                  a[mt][kh], b[nh_][nf][kh], acc[(mh_) * 4 + mt][(nh_) * 2 + nf], 0, 0, 0); \
    __builtin_amdgcn_s_setprio(0);                                              \
  } while (0)

#define GATE4 asm volatile("s_waitcnt vmcnt(4)" ::: "memory")
#define GATE2 asm volatile("s_waitcnt vmcnt(2)" ::: "memory")
#define GATE0 asm volatile("s_waitcnt vmcnt(0)" ::: "memory")
#define BAR                                                                     \
  do {                                                                          \
    asm volatile("" ::: "memory");                                              \
    __builtin_amdgcn_s_barrier();                                               \
    asm volatile("" ::: "memory");                                              \
  } while (0)

  // prologue: stage tile 0 fully into buffer 0 (order Alo,Blo,Bhi,Ahi)
  STAGE_HALF(Xb, As0, i0, 0, 0);
  STAGE_HALF(W,  Bs0, j0, 0, 0);
  STAGE_HALF(W,  Bs0, j0, 0, 1);
  STAGE_HALF(Xb, As0, i0, 0, 1);
  GATE0;
  BAR;

  for (int t = 0; t < 11; t++) {
    const unsigned short* Ar = (t & 1) ? As1 : As0;
    const unsigned short* Br = (t & 1) ? Bs1 : Bs0;
    unsigned short* Aw = (t & 1) ? As0 : As1;
    unsigned short* Bw = (t & 1) ? Bs0 : Bs1;
    const int k0n = (t + 1) * 64;

    // phase 0: Q00  (reads Alo,Blo of t; stages Alo of t+1)
    READ_A(0); READ_B(0);
    STAGE_HALF(Xb, Aw, i0, k0n, 0);
    GATE4; BAR;
    MFMA16(0, 0);
    BAR;

    // phase 1: Q01  (reads Bhi of t; stages Blo of t+1)
    READ_B(1);
    STAGE_HALF(W, Bw, j0, k0n, 0);
    GATE4; BAR;
    MFMA16(0, 1);
    BAR;

    // phase 2: Q10  (reads Ahi of t; stages Bhi of t+1)
    if (!skipHi) READ_A(1);
    STAGE_HALF(W, Bw, j0, k0n, 1);
    BAR;
    if (!skipHi) MFMA16(1, 0);
    BAR;

    // phase 3: Q11  (stages Ahi of t+1)
    STAGE_HALF(Xb, Aw, i0, k0n, 1);
    GATE4; BAR;
    if (!skipHi) MFMA16(1, 1);
    BAR;
  }

  // peeled last tile (t=11, buffers As1/Bs1, no staging; drain gates)
  {
    const unsigned short* Ar = As1;
    const unsigned short* Br = Bs1;
    READ_A(0); READ_B(0);
    GATE2; BAR;
    MFMA16(0, 0);
    BAR;
    READ_B(1);
    GATE0; BAR;
    MFMA16(0, 1);
    if (!skipHi) {
      READ_A(1);
      MFMA16(1, 0);
      MFMA16(1, 1);
    }
  }

  // ---------------- epilogue ----------------
  const int b_ = blockIdx.x / 3;
  float colsum[4] = {0.f, 0.f, 0.f, 0.f};
#pragma unroll
  for (int mf = 0; mf < 8; mf++) {
    if (skipHi && mf >= 4) continue;
    const int rloc = (mf >> 2) * 128 + wr * 64 + (mf & 3) * 16;
#pragma unroll
    for (int nf = 0; nf < 4; nf++) {
      const int j = j0 + (nf >> 1) * 128 + wc * 32 + (nf & 1) * 16 + col;
      const float bj = bias[j];
#pragma unroll
      for (int r = 0; r < 4; r++) {
        const int iloc = rloc + quad * 4 + r;
        const int i = i0 + iloc;
        const float v = acc[mf][nf][r] + bj;
        Y[(size_t)i * H + j] = f2bf(v);
        if (z == 2) {
          colsum[nf] += v;
          const int s = xb3 * 256 + iloc;
          if (s >= SQ) out[(size_t)i * H + j] = v;  // tail rows: out = V row
        }
      }
    }
  }
  if (z == 2) {
#pragma unroll
    for (int nf = 0; nf < 4; nf++) {
      float s = colsum[nf];
      s += __shfl_xor(s, 16, 64);
      s += __shfl_xor(s, 32, 64);
      if (quad == 0) {
        const int j = j0 + (nf >> 1) * 128 + wc * 32 + (nf & 1) * 16 + col;
        atomicAdd(&part[b_ * H + j], s);
      }
    }
  }
#undef STAGE_HALF
#undef READ_A
#undef READ_B
#undef MFMA16
#undef GATE4
#undef GATE2
#undef GATE0
#undef BAR
}

// ---------------- fused masked attention ----------------
// One block per (b, h, chunk c). 192 live keys = chunk(64) + tail(128).
// Masked keys have score exactly 0 (multiplicative mask), handled in closed form:
//   m = max(0, max live s);  Z = sum live e^(s-m) + 576 e^-m
//   ctx = (sum live e^(s-m) v + e^-m (Vtot - sum staged v)) / Z
__launch_bounds__(256, 2)
__global__ void attn_kernel(const unsigned short* __restrict__ Qb,
                            const unsigned short* __restrict__ Kb,
                            const unsigned short* __restrict__ Vb,
                            const float* __restrict__ part,
                            float* __restrict__ out) {
  const int bid = blockIdx.x;
  const int c = bid % CDD;
  const int h = (bid / CDD) % NH;
  const int b = bid / (CDD * NH);
  const int tid = threadIdx.x;
  const int wave = tid >> 6, lane = tid & 63;
  const int col = lane & 15, quad = lane >> 4;

  __shared__ __align__(16) char smem[59136];
  unsigned short* Qs = (unsigned short*)smem;            // 64x64 (stride 64, swizzled), 8KB
  unsigned short* Ks = (unsigned short*)(smem + 8192);   // 192x64 (stride 64, swizzled), 24KB
  unsigned short* Ps = (unsigned short*)smem;            // 64 x stride196 bf16 (aliases Qs+Ks)
  unsigned short* Vt = (unsigned short*)(smem + 32768);  // 64 x stride196 (V transposed)
  float* red   = (float*)(smem + 57856);                 // 256 f
  float* vcorr = (float*)(smem + 58880);                 // 64 f

  const size_t rowQ0 = (size_t)(b * S + c * 64) * H + h * DH;

  // --- stage Q (512 slots), K (1536 slots) via global_load_lds, swizzle ^(row&7)
  {
    int s0 = tid, s1 = tid + 256;
    int r0 = s0 >> 3, g0 = (s0 & 7) ^ (r0 & 7);
    int r1 = s1 >> 3, g1 = (s1 & 7) ^ (r1 & 7);
    gld_lds16(Qb + rowQ0 + (size_t)r0 * H + g0 * 8, &Qs[s0 * 8]);
    gld_lds16(Qb + rowQ0 + (size_t)r1 * H + g1 * 8, &Qs[s1 * 8]);
  }
#pragma unroll
  for (int j = 0; j < 6; j++) {
    int s = tid + 256 * j;
    int key = s >> 3;
    int gkey = (key < 64) ? (c * 64 + key) : (576 + key);
    int gc = (s & 7) ^ (key & 7);
    gld_lds16(Kb + (size_t)(b * S + gkey) * H + h * DH + gc * 8, &Ks[s * 8]);
  }
  // --- stage V transposed: Vt[d][key], stride 196 (196%8==4 breaks write conflicts)
#pragma unroll
  for (int j = 0; j < 6; j++) {
    int s = tid + 256 * j;
    int key = s >> 3;
    int f0 = (s & 7) * 8;
    int gkey = (key < 64) ? (c * 64 + key) : (576 + key);
    union { int4 i4; unsigned short u[8]; } uv;
    uv.i4 = *(const int4*)(Vb + (size_t)(b * S + gkey) * H + h * DH + f0);
#pragma unroll
    for (int i = 0; i < 8; i++) Vt[(f0 + i) * 196 + key] = uv.u[i];
  }
  __builtin_amdgcn_s_waitcnt(0);
  __syncthreads();

  // --- staged-V column sums (for the masked correction)
  {
    int d = tid & 63, p = tid >> 6;
    float sum = 0.f;
    for (int k = p * 48; k < p * 48 + 48; k++) sum += bf2f(Vt[d * 196 + k]);
    red[tid] = sum;
  }
  __syncthreads();
  if (tid < 64) {
    float tot = part[b * H + h * DH + tid];
    vcorr[tid] = tot - (red[tid] + red[64 + tid] + red[128 + tid] + red[192 + tid]);
  }

  // --- QK^T: wave handles q-rows [wave*16, wave*16+16), 12 col-tiles, K=64
  f32x4 sc[12];
#pragma unroll
  for (int n = 0; n < 12; n++) sc[n] = (f32x4){0.f, 0.f, 0.f, 0.f};
  {
    const int rq = wave * 16 + col;
    bf16x8 a0 = *(const bf16x8*)&Qs[rq * 64 + ((quad ^ (rq & 7)) * 8)];
    bf16x8 a1 = *(const bf16x8*)&Qs[rq * 64 + (((4 + quad) ^ (rq & 7)) * 8)];
#pragma unroll
    for (int n = 0; n < 12; n++) {
      const int rk = n * 16 + col;
      bf16x8 b0 = *(const bf16x8*)&Ks[rk * 64 + ((quad ^ (rk & 7)) * 8)];
      bf16x8 b1 = *(const bf16x8*)&Ks[rk * 64 + (((4 + quad) ^ (rk & 7)) * 8)];
      sc[n] = __builtin_amdgcn_mfma_f32_16x16x32_bf16(a0, b0, sc[n], 0, 0, 0);
      sc[n] = __builtin_amdgcn_mfma_f32_16x16x32_bf16(a1, b1, sc[n], 0, 0, 0);
    }
  }

  // --- masked softmax (exact, multiplicative-mask semantics)
  float em[4], zin[4];
  {
    const float scale = 0.125f;  // 1/sqrt(64)
#pragma unroll
    for (int r = 0; r < 4; r++) {
      float mx = sc[0][r];
#pragma unroll
      for (int n = 1; n < 12; n++) mx = fmaxf(mx, sc[n][r]);
#pragma unroll
      for (int msk = 1; msk <= 8; msk <<= 1) mx = fmaxf(mx, __shfl_xor(mx, msk, 64));
      const float mrow = fmaxf(mx * scale, 0.f);
      float rs = 0.f;
#pragma unroll
      for (int n = 0; n < 12; n++) {
        float p = __expf(sc[n][r] * scale - mrow);
        sc[n][r] = p;
        rs += p;
      }
#pragma unroll
      for (int msk = 1; msk <= 8; msk <<= 1) rs += __shfl_xor(rs, msk, 64);
      const float e = __expf(-mrow);
      em[r] = e;
      zin[r] = 1.f / (rs + 576.f * e);
    }
  }
  __syncthreads();  // all Qs/Ks reads done before Ps (aliased) writes; vcorr visible

  // --- P -> LDS (bf16, stride 196)
#pragma unroll
  for (int n = 0; n < 12; n++)
#pragma unroll
    for (int r = 0; r < 4; r++)
      Ps[(wave * 16 + quad * 4 + r) * 196 + n * 16 + col] = f2bf(sc[n][r]);
  __syncthreads();

  // --- PV: wave rows [wave*16,+16) x 64 cols, K=192
  f32x4 o[4];
#pragma unroll
  for (int n2 = 0; n2 < 4; n2++) o[n2] = (f32x4){0.f, 0.f, 0.f, 0.f};
#pragma unroll
  for (int ks = 0; ks < 6; ks++) {
    bf16x8 a = ld_b64x2(&Ps[(wave * 16 + col) * 196 + ks * 32 + quad * 8]);
#pragma unroll
    for (int n2 = 0; n2 < 4; n2++) {
      bf16x8 bvv = ld_b64x2(&Vt[(n2 * 16 + col) * 196 + ks * 32 + quad * 8]);
      o[n2] = __builtin_amdgcn_mfma_f32_16x16x32_bf16(a, bvv, o[n2], 0, 0, 0);
    }
  }

  // --- epilogue: add masked-V correction, normalize, store fp32
#pragma unroll
  for (int n2 = 0; n2 < 4; n2++) {
    const int d = n2 * 16 + col;
    const float vc = vcorr[d];
#pragma unroll
    for (int r = 0; r < 4; r++) {
      const int m = wave * 16 + quad * 4 + r;
      const float val = (o[n2][r] + em[r] * vc) * zin[r];
      out[(size_t)(b * S + c * 64 + m) * H + h * DH + d] = val;
    }
  }
}

extern "C" void kernel_launch(void* const* d_in, const int* in_sizes, int n_in,
                              void* d_out, int out_size, void* d_ws, size_t ws_size,
                              hipStream_t stream) {
  const float* X  = (const float*)d_in[0];
  const float* Wq = (const float*)d_in[1];
  const float* bq = (const float*)d_in[2];
  const float* Wk = (const float*)d_in[3];
  const float* bk = (const float*)d_in[4];
  const float* Wv = (const float*)d_in[5];
  const float* bv = (const float*)d_in[6];
  float* out = (float*)d_out;

  char* ws = (char*)d_ws;
  // workspace layout (~75.5 MB total)
  unsigned short* Xb   = (unsigned short*)ws;                    // 12288x768 bf16
  unsigned short* Wb   = (unsigned short*)(ws + 18874368);       // 3x768x768 bf16
  unsigned short* Qb   = (unsigned short*)(ws + 22413312);       // 12288x768 bf16
  unsigned short* Kb   = (unsigned short*)(ws + 41287680);
  unsigned short* Vb   = (unsigned short*)(ws + 60162048);
  float*          part = (float*)(ws + 79036416);                // 16x768 f32 (atomic)

  hipMemsetAsync(part, 0, Bb * H * sizeof(float), stream);
  convert_all<<<2048, 256, 0, stream>>>(X, Wq, Wk, Wv, Xb, Wb);
  qkv_gemm<<<dim3(48, 9), 512, 0, stream>>>(Xb, Wb, bq, bk, bv, Qb, Kb, Vb, part, out);
  attn_kernel<<<1920, 256, 0, stream>>>(Qb, Kb, Vb, part, out);
}

// Round 4
// 184.450 us; speedup vs baseline: 1.0167x; 1.0167x over previous
//
#include <hip/hip_runtime.h>

// Problem constants
constexpr int Bb  = 16;
constexpr int CDD = 10;
constexpr int Lc  = 64;
constexpr int T   = 128;
constexpr int H   = 768;
constexpr int NH  = 12;
constexpr int DH  = 64;    // H/NH
constexpr int S   = 768;   // CDD*Lc + T
constexpr int SQ  = 640;   // CDD*Lc
constexpr int MROWS = Bb * S;  // 12288

typedef __attribute__((ext_vector_type(8))) short bf16x8;
typedef __attribute__((ext_vector_type(4))) short bf16x4;
typedef __attribute__((ext_vector_type(4))) float f32x4;

__device__ inline unsigned short f2bf(float f) {
  unsigned u = __float_as_uint(f);
  u += 0x7fff + ((u >> 16) & 1);   // RNE
  return (unsigned short)(u >> 16);
}
__device__ inline float bf2f(unsigned short h) {
  return __uint_as_float(((unsigned)h) << 16);
}

__device__ inline void gld_lds16(const void* g, void* l) {
  __builtin_amdgcn_global_load_lds(
      (const __attribute__((address_space(1))) void*)g,
      (__attribute__((address_space(3))) void*)l, 16, 0, 0);
}

__device__ inline bf16x8 ld_b64x2(const unsigned short* p) {
  union { bf16x8 v; bf16x4 h[2]; } u;
  u.h[0] = *(const bf16x4*)p;
  u.h[1] = *(const bf16x4*)(p + 4);
  return u.v;
}

// ---------------- fp32 -> bf16 convert (X + 3 weights, one launch) ------------
constexpr int NX4 = MROWS * H / 4;   // 2359296 float4s
constexpr int NW4 = H * H / 4;       // 147456 float4s
__global__ void convert_all(const float* __restrict__ X,
                            const float* __restrict__ Wq,
                            const float* __restrict__ Wk,
                            const float* __restrict__ Wv,
                            unsigned short* __restrict__ Xb,
                            unsigned short* __restrict__ Wb) {
  int i = blockIdx.x * blockDim.x + threadIdx.x;
  const int stride = gridDim.x * blockDim.x;
  const int total = NX4 + 3 * NW4;
  for (; i < total; i += stride) {
    const float* src;
    unsigned short* dst;
    int off;
    if (i < NX4) {
      src = X; dst = Xb; off = i;
    } else {
      int k = i - NX4;
      int w = k / NW4;
      off = k - w * NW4;
      src = (w == 0) ? Wq : (w == 1) ? Wk : Wv;
      dst = Wb + (size_t)w * H * H;
    }
    float4 v = ((const float4*)src)[off];
    ushort4 o;
    o.x = f2bf(v.x); o.y = f2bf(v.y); o.z = f2bf(v.z); o.w = f2bf(v.w);
    ((ushort4*)dst)[off] = o;
  }
}

// ---------------- QKV projection GEMM: Y = X * W^T + bias ----------------
// M=12288, N=2304 (z merged into grid.y), K=768.
// 256x256 tile, BK=64 (12 K-tiles), 512 threads = 8 waves.
// Interleaved wave ownership: wave wr owns rows [wr*64,+64) u [128+wr*64,+64),
// wave wc owns cols [wc*32,+32) u [128+wc*32,+32)  ->  quadrant (mh,nh) is
// computed by ALL waves from half-tiles {A(mh), B(nh)}.
//
// DEEP-STAGGER SCHEDULE (half-tile-granular double buffer):
//   phase p of tile t computes quadrant: p0:Q00 (reads Alo,Blo), p1:Q01 (Bhi),
//   p2:Q10 (Ahi), p3:Q11 (cached frags only).
//   staging: p0: Ahi(t+1); p1: Alo(t+2); p2: Blo(t+2); p3: Bhi(t+2)
//   -> every gated load was issued 5-6 phases (~1500+ cyc) before its gate:
//      above HBM latency, so gates never stall (r2's bug: 2-phase slack).
//   gates (uniform, verified by outstanding-count): vmcnt(10) at p0,p1,p3; none p2.
//   INVARIANT: gate -> barrier -> read. Cross-wave LDS visibility of staged
//   data requires ALL waves to pass their gate before ANY wave reads (r3's
//   NaN bug: gate->read with no barrier between).
//   ONE barrier per phase: lgkmcnt(0) before the barrier guarantees all
//   waves' ds_reads completed before any wave issues next phase's stage into
//   the just-read half (the WAR hazard that otherwise needs a 2nd barrier).
//   Half-overwrite distance >= 1 phase by construction:
//     Ahi(t+1)@p0(t) overwrites Ahi(t-1) (read p2(t-1));
//     Alo(t+2)@p1(t) overwrites Alo(t) (read p0(t)); etc.
__launch_bounds__(512, 2)
__global__ void qkv_gemm(const unsigned short* __restrict__ Xb,
                         const unsigned short* __restrict__ Wb,
                         const float* __restrict__ bq, const float* __restrict__ bk,
                         const float* __restrict__ bv,
                         unsigned short* __restrict__ Qb, unsigned short* __restrict__ Kb,
                         unsigned short* __restrict__ Vb,
                         float* __restrict__ part,
                         float* __restrict__ out) {
  const int z  = blockIdx.y / 3;
  const int j0 = (blockIdx.y % 3) * 256;
  const int i0 = blockIdx.x * 256;
  const int xb3 = blockIdx.x % 3;        // which 256-row third of the batch
  const unsigned short* W = Wb + (size_t)z * H * H;
  const float* bias = (z == 0) ? bq : (z == 1) ? bk : bv;
  unsigned short* Y = (z == 0) ? Qb : (z == 1) ? Kb : Vb;

  const int tid = threadIdx.x;
  const int wave = tid >> 6, lane = tid & 63;
  const int wr = wave >> 2, wc = wave & 3;      // wr 0..1 (M), wc 0..3 (N)
  const int col = lane & 15, quad = lane >> 4;

  // Q tail rows (640..767 of each batch) = mh==1 quadrants of xb3==2 tiles:
  // never consumed by attention -> skip those quadrants (block-uniform).
  const bool skipHi = (z == 0) && (xb3 == 2);

  // double-buffered A/B tiles, 256 rows x 64 cols bf16 each (128 KiB total);
  // tile t lives in parity t&1; halves (rows 0-127 / 128-255) recycled
  // independently per the stagger schedule.
  __shared__ unsigned short As0[256 * 64];
  __shared__ unsigned short As1[256 * 64];
  __shared__ unsigned short Bs0[256 * 64];
  __shared__ unsigned short Bs1[256 * 64];

  f32x4 acc[8][4];
#pragma unroll
  for (int i = 0; i < 8; i++)
#pragma unroll
    for (int j = 0; j < 4; j++) acc[i][j] = (f32x4){0.f, 0.f, 0.f, 0.f};

  bf16x8 a[4][2];      // A frags of current mh (mt, kh)
  bf16x8 b[2][2][2];   // B frags (nh, nf, kh) -- cached across mh phases

#define STAGE_HALF(src, dst, rowbase, k0, hf)                                   \
  do {                                                                          \
    _Pragma("unroll") for (int u = 0; u < 2; u++) {                             \
      const int s_ = tid + 512 * u;                                             \
      const int r_ = (s_ >> 3) + (hf) * 128;                                    \
      const int c_ = s_ & 7;                                                    \
      gld_lds16((src) + (size_t)((rowbase) + r_) * H + (k0) + ((c_ ^ (r_ & 7)) * 8), \
                &(dst)[(r_ * 8 + c_) * 8]);                                     \
    }                                                                           \
  } while (0)

#define READ_A(mh_)                                                             \
  do {                                                                          \
    _Pragma("unroll") for (int mt = 0; mt < 4; mt++) {                          \
      const int r_ = (mh_) * 128 + wr * 64 + mt * 16 + col;                     \
      _Pragma("unroll") for (int kh = 0; kh < 2; kh++)                          \
        a[mt][kh] = *(const bf16x8*)&Ar[r_ * 64 + (((kh * 4 + quad) ^ (r_ & 7)) * 8)]; \
    }                                                                           \
  } while (0)

#define READ_B(nh_)                                                             \
  do {                                                                          \
    _Pragma("unroll") for (int nf = 0; nf < 2; nf++) {                          \
      const int r_ = (nh_) * 128 + wc * 32 + nf * 16 + col;                     \
      _Pragma("unroll") for (int kh = 0; kh < 2; kh++)                          \
        b[nh_][nf][kh] = *(const bf16x8*)&Br[r_ * 64 + (((kh * 4 + quad) ^ (r_ & 7)) * 8)]; \
    }                                                                           \
  } while (0)

#define MFMA16(mh_, nh_)                                                        \
  do {                                                                          \
    __builtin_amdgcn_s_setprio(1);                                              \
    _Pragma("unroll") for (int mt = 0; mt < 4; mt++)                            \
      _Pragma("unroll") for (int nf = 0; nf < 2; nf++)                          \
        _Pragma("unroll") for (int kh = 0; kh < 2; kh++)                        \
          acc[(mh_) * 4 + mt][(nh_) * 2 + nf] =                                 \
              __builtin_amdgcn_mfma_f32_16x16x32_bf16(                          \
                  a[mt][kh], b[nh_][nf][kh], acc[(mh_) * 4 + mt][(nh_) * 2 + nf], 0, 0, 0); \
    __builtin_amdgcn_s_setprio(0);                                              \
  } while (0)

  // gate + read-completion fence + barrier (one per phase).
  // vm literal = loads left in flight after the gate (counted per schedule).
#define PHASE_SYNC(vm)                                                          \
  do {                                                                          \
    asm volatile("s_waitcnt vmcnt(" #vm ") lgkmcnt(0)" ::: "memory");           \
    __builtin_amdgcn_sched_barrier(0);                                          \
    __builtin_amdgcn_s_barrier();                                               \
  } while (0)
#define PHASE_SYNC_NOVM                                                         \
  do {                                                                          \
    asm volatile("s_waitcnt lgkmcnt(0)" ::: "memory");                          \
    __builtin_amdgcn_sched_barrier(0);                                          \
    __builtin_amdgcn_s_barrier();                                               \
  } while (0)

  // prologue: stage Alo(0),Blo(0),Bhi(0),Ahi(0),Alo(1),Blo(1),Bhi(1)
  // (14 loads); gate retires Alo(0),Blo(0) -> vmcnt(10).
  STAGE_HALF(Xb, As0, i0, 0, 0);
  STAGE_HALF(W,  Bs0, j0, 0, 0);
  STAGE_HALF(W,  Bs0, j0, 0, 1);
  STAGE_HALF(Xb, As0, i0, 0, 1);
  STAGE_HALF(Xb, As1, i0, 64, 0);
  STAGE_HALF(W,  Bs1, j0, 64, 0);
  STAGE_HALF(W,  Bs1, j0, 64, 1);
  PHASE_SYNC(10);

  for (int t = 0; t < 10; t++) {
    const unsigned short* Ar = (t & 1) ? As1 : As0;
    const unsigned short* Br = (t & 1) ? Bs1 : Bs0;
    unsigned short* Acur = (t & 1) ? As1 : As0;   // parity t  (== t+2)
    unsigned short* Bcur = (t & 1) ? Bs1 : Bs0;
    unsigned short* Anxt = (t & 1) ? As0 : As1;   // parity t+1

    // ph0: Q00 (reads Alo,Blo of t); stage Ahi(t+1); gate protects ph1's Bhi(t)
    READ_A(0); READ_B(0);
    STAGE_HALF(Xb, Anxt, i0, (t + 1) * 64, 1);
    PHASE_SYNC(10);
    MFMA16(0, 0);

    // ph1: Q01 (reads Bhi of t); stage Alo(t+2); gate protects ph2's Ahi(t)
    READ_B(1);
    STAGE_HALF(Xb, Acur, i0, (t + 2) * 64, 0);
    PHASE_SYNC(10);
    MFMA16(0, 1);

    // ph2: Q10 (reads Ahi of t); stage Blo(t+2); no gate needed
    if (!skipHi) READ_A(1);
    STAGE_HALF(W, Bcur, j0, (t + 2) * 64, 0);
    PHASE_SYNC_NOVM;
    if (!skipHi) MFMA16(1, 0);

    // ph3: Q11 (cached frags); stage Bhi(t+2); gate protects ph0(t+1)'s Alo,Blo
    STAGE_HALF(W, Bcur, j0, (t + 2) * 64, 1);
    PHASE_SYNC(10);
    if (!skipHi) MFMA16(1, 1);
  }

  // peeled t=10 (parity 0; only Ahi(11) left to stage; drain 10 -> 8 -> 4)
  {
    const unsigned short* Ar = As0;
    const unsigned short* Br = Bs0;
    READ_A(0); READ_B(0);
    STAGE_HALF(Xb, As1, i0, 11 * 64, 1);   // Ahi(11)
    PHASE_SYNC(10);
    MFMA16(0, 0);

    READ_B(1);
    PHASE_SYNC(8);
    MFMA16(0, 1);

    if (!skipHi) READ_A(1);
    PHASE_SYNC_NOVM;
    if (!skipHi) MFMA16(1, 0);

    PHASE_SYNC(4);                          // protects ph0(11)'s Alo,Blo
    if (!skipHi) MFMA16(1, 1);
  }
  // peeled t=11 (parity 1; no staging; drain 2 -> 0)
  {
    const unsigned short* Ar = As1;
    const unsigned short* Br = Bs1;
    READ_A(0); READ_B(0);
    PHASE_SYNC(2);                          // protects Bhi(11)
    MFMA16(0, 0);

    READ_B(1);
    PHASE_SYNC(0);                          // protects Ahi(11)
    MFMA16(0, 1);

    if (!skipHi) {
      READ_A(1);
      MFMA16(1, 0);
      MFMA16(1, 1);
    }
  }

  // ---------------- epilogue ----------------
  const int b_ = blockIdx.x / 3;
  float colsum[4] = {0.f, 0.f, 0.f, 0.f};
#pragma unroll
  for (int mf = 0; mf < 8; mf++) {
    if (skipHi && mf >= 4) continue;
    const int rloc = (mf >> 2) * 128 + wr * 64 + (mf & 3) * 16;
#pragma unroll
    for (int nf = 0; nf < 4; nf++) {
      const int j = j0 + (nf >> 1) * 128 + wc * 32 + (nf & 1) * 16 + col;
      const float bj = bias[j];
#pragma unroll
      for (int r = 0; r < 4; r++) {
        const int iloc = rloc + quad * 4 + r;
        const int i = i0 + iloc;
        const float v = acc[mf][nf][r] + bj;
        Y[(size_t)i * H + j] = f2bf(v);
        if (z == 2) {
          colsum[nf] += v;
          const int s = xb3 * 256 + iloc;
          if (s >= SQ) out[(size_t)i * H + j] = v;  // tail rows: out = V row
        }
      }
    }
  }
  if (z == 2) {
#pragma unroll
    for (int nf = 0; nf < 4; nf++) {
      float s = colsum[nf];
      s += __shfl_xor(s, 16, 64);
      s += __shfl_xor(s, 32, 64);
      if (quad == 0) {
        const int j = j0 + (nf >> 1) * 128 + wc * 32 + (nf & 1) * 16 + col;
        atomicAdd(&part[b_ * H + j], s);
      }
    }
  }
#undef STAGE_HALF
#undef READ_A
#undef READ_B
#undef MFMA16
#undef PHASE_SYNC
#undef PHASE_SYNC_NOVM
}

// ---------------- fused masked attention ----------------
// One block per (b, h, chunk c). 192 live keys = chunk(64) + tail(128).
// Masked keys have score exactly 0 (multiplicative mask), handled in closed form:
//   m = max(0, max live s);  Z = sum live e^(s-m) + 576 e^-m
//   ctx = (sum live e^(s-m) v + e^-m (Vtot - sum staged v)) / Z
__launch_bounds__(256, 2)
__global__ void attn_kernel(const unsigned short* __restrict__ Qb,
                            const unsigned short* __restrict__ Kb,
                            const unsigned short* __restrict__ Vb,
                            const float* __restrict__ part,
                            float* __restrict__ out) {
  const int bid = blockIdx.x;
  const int c = bid % CDD;
  const int h = (bid / CDD) % NH;
  const int b = bid / (CDD * NH);
  const int tid = threadIdx.x;
  const int wave = tid >> 6, lane = tid & 63;
  const int col = lane & 15, quad = lane >> 4;

  __shared__ __align__(16) char smem[59136];
  unsigned short* Qs = (unsigned short*)smem;            // 64x64 (stride 64, swizzled), 8KB
  unsigned short* Ks = (unsigned short*)(smem + 8192);   // 192x64 (stride 64, swizzled), 24KB
  unsigned short* Ps = (unsigned short*)smem;            // 64 x stride196 bf16 (aliases Qs+Ks)
  unsigned short* Vt = (unsigned short*)(smem + 32768);  // 64 x stride196 (V transposed)
  float* red   = (float*)(smem + 57856);                 // 256 f
  float* vcorr = (float*)(smem + 58880);                 // 64 f

  const size_t rowQ0 = (size_t)(b * S + c * 64) * H + h * DH;

  // --- stage Q (512 slots), K (1536 slots) via global_load_lds, swizzle ^(row&7)
  {
    int s0 = tid, s1 = tid + 256;
    int r0 = s0 >> 3, g0 = (s0 & 7) ^ (r0 & 7);
    int r1 = s1 >> 3, g1 = (s1 & 7) ^ (r1 & 7);
    gld_lds16(Qb + rowQ0 + (size_t)r0 * H + g0 * 8, &Qs[s0 * 8]);
    gld_lds16(Qb + rowQ0 + (size_t)r1 * H + g1 * 8, &Qs[s1 * 8]);
  }
#pragma unroll
  for (int j = 0; j < 6; j++) {
    int s = tid + 256 * j;
    int key = s >> 3;
    int gkey = (key < 64) ? (c * 64 + key) : (576 + key);
    int gc = (s & 7) ^ (key & 7);
    gld_lds16(Kb + (size_t)(b * S + gkey) * H + h * DH + gc * 8, &Ks[s * 8]);
  }
  // --- stage V transposed: Vt[d][key], stride 196 (196%8==4 breaks write conflicts)
#pragma unroll
  for (int j = 0; j < 6; j++) {
    int s = tid + 256 * j;
    int key = s >> 3;
    int f0 = (s & 7) * 8;
    int gkey = (key < 64) ? (c * 64 + key) : (576 + key);
    union { int4 i4; unsigned short u[8]; } uv;
    uv.i4 = *(const int4*)(Vb + (size_t)(b * S + gkey) * H + h * DH + f0);
#pragma unroll
    for (int i = 0; i < 8; i++) Vt[(f0 + i) * 196 + key] = uv.u[i];
  }
  __builtin_amdgcn_s_waitcnt(0);
  __syncthreads();

  // --- staged-V column sums (for the masked correction)
  {
    int d = tid & 63, p = tid >> 6;
    float sum = 0.f;
    for (int k = p * 48; k < p * 48 + 48; k++) sum += bf2f(Vt[d * 196 + k]);
    red[tid] = sum;
  }
  __syncthreads();
  if (tid < 64) {
    float tot = part[b * H + h * DH + tid];
    vcorr[tid] = tot - (red[tid] + red[64 + tid] + red[128 + tid] + red[192 + tid]);
  }

  // --- QK^T: wave handles q-rows [wave*16, wave*16+16), 12 col-tiles, K=64
  f32x4 sc[12];
#pragma unroll
  for (int n = 0; n < 12; n++) sc[n] = (f32x4){0.f, 0.f, 0.f, 0.f};
  {
    const int rq = wave * 16 + col;
    bf16x8 a0 = *(const bf16x8*)&Qs[rq * 64 + ((quad ^ (rq & 7)) * 8)];
    bf16x8 a1 = *(const bf16x8*)&Qs[rq * 64 + (((4 + quad) ^ (rq & 7)) * 8)];
#pragma unroll
    for (int n = 0; n < 12; n++) {
      const int rk = n * 16 + col;
      bf16x8 b0 = *(const bf16x8*)&Ks[rk * 64 + ((quad ^ (rk & 7)) * 8)];
      bf16x8 b1 = *(const bf16x8*)&Ks[rk * 64 + (((4 + quad) ^ (rk & 7)) * 8)];
      sc[n] = __builtin_amdgcn_mfma_f32_16x16x32_bf16(a0, b0, sc[n], 0, 0, 0);
      sc[n] = __builtin_amdgcn_mfma_f32_16x16x32_bf16(a1, b1, sc[n], 0, 0, 0);
    }
  }

  // --- masked softmax (exact, multiplicative-mask semantics)
  float em[4], zin[4];
  {
    const float scale = 0.125f;  // 1/sqrt(64)
#pragma unroll
    for (int r = 0; r < 4; r++) {
      float mx = sc[0][r];
#pragma unroll
      for (int n = 1; n < 12; n++) mx = fmaxf(mx, sc[n][r]);
#pragma unroll
      for (int msk = 1; msk <= 8; msk <<= 1) mx = fmaxf(mx, __shfl_xor(mx, msk, 64));
      const float mrow = fmaxf(mx * scale, 0.f);
      float rs = 0.f;
#pragma unroll
      for (int n = 0; n < 12; n++) {
        float p = __expf(sc[n][r] * scale - mrow);
        sc[n][r] = p;
        rs += p;
      }
#pragma unroll
      for (int msk = 1; msk <= 8; msk <<= 1) rs += __shfl_xor(rs, msk, 64);
      const float e = __expf(-mrow);
      em[r] = e;
      zin[r] = 1.f / (rs + 576.f * e);
    }
  }
  __syncthreads();  // all Qs/Ks reads done before Ps (aliased) writes; vcorr visible

  // --- P -> LDS (bf16, stride 196)
#pragma unroll
  for (int n = 0; n < 12; n++)
#pragma unroll
    for (int r = 0; r < 4; r++)
      Ps[(wave * 16 + quad * 4 + r) * 196 + n * 16 + col] = f2bf(sc[n][r]);
  __syncthreads();

  // --- PV: wave rows [wave*16,+16) x 64 cols, K=192
  f32x4 o[4];
#pragma unroll
  for (int n2 = 0; n2 < 4; n2++) o[n2] = (f32x4){0.f, 0.f, 0.f, 0.f};
#pragma unroll
  for (int ks = 0; ks < 6; ks++) {
    bf16x8 a = ld_b64x2(&Ps[(wave * 16 + col) * 196 + ks * 32 + quad * 8]);
#pragma unroll
    for (int n2 = 0; n2 < 4; n2++) {
      bf16x8 bvv = ld_b64x2(&Vt[(n2 * 16 + col) * 196 + ks * 32 + quad * 8]);
      o[n2] = __builtin_amdgcn_mfma_f32_16x16x32_bf16(a, bvv, o[n2], 0, 0, 0);
    }
  }

  // --- epilogue: add masked-V correction, normalize, store fp32
#pragma unroll
  for (int n2 = 0; n2 < 4; n2++) {
    const int d = n2 * 16 + col;
    const float vc = vcorr[d];
#pragma unroll
    for (int r = 0; r < 4; r++) {
      const int m = wave * 16 + quad * 4 + r;
      const float val = (o[n2][r] + em[r] * vc) * zin[r];
      out[(size_t)(b * S + c * 64 + m) * H + h * DH + d] = val;
    }
  }
}

extern "C" void kernel_launch(void* const* d_in, const int* in_sizes, int n_in,
                              void* d_out, int out_size, void* d_ws, size_t ws_size,
                              hipStream_t stream) {
  const float* X  = (const float*)d_in[0];
  const float* Wq = (const float*)d_in[1];
  const float* bq = (const float*)d_in[2];
  const float* Wk = (const float*)d_in[3];
  const float* bk = (const float*)d_in[4];
  const float* Wv = (const float*)d_in[5];
  const float* bv = (const float*)d_in[6];
  float* out = (float*)d_out;

  char* ws = (char*)d_ws;
  // workspace layout (~75.5 MB total)
  unsigned short* Xb   = (unsigned short*)ws;                    // 12288x768 bf16
  unsigned short* Wb   = (unsigned short*)(ws + 18874368);       // 3x768x768 bf16
  unsigned short* Qb   = (unsigned short*)(ws + 22413312);       // 12288x768 bf16
  unsigned short* Kb   = (unsigned short*)(ws + 41287680);
  unsigned short* Vb   = (unsigned short*)(ws + 60162048);
  float*          part = (float*)(ws + 79036416);                // 16x768 f32 (atomic)

  hipMemsetAsync(part, 0, Bb * H * sizeof(float), stream);
  convert_all<<<2048, 256, 0, stream>>>(X, Wq, Wk, Wv, Xb, Wb);
  qkv_gemm<<<dim3(48, 9), 512, 0, stream>>>(Xb, Wb, bq, bk, bv, Qb, Kb, Vb, part, out);
  attn_kernel<<<1920, 256, 0, stream>>>(Qb, Kb, Vb, part, out);
}

// Round 5
// 178.553 us; speedup vs baseline: 1.0503x; 1.0330x over previous
//
#include <hip/hip_runtime.h>

// Problem constants
constexpr int Bb  = 16;
constexpr int CDD = 10;
constexpr int Lc  = 64;
constexpr int T   = 128;
constexpr int H   = 768;
constexpr int NH  = 12;
constexpr int DH  = 64;    // H/NH
constexpr int S   = 768;   // CDD*Lc + T
constexpr int SQ  = 640;   // CDD*Lc
constexpr int MROWS = Bb * S;  // 12288

typedef __attribute__((ext_vector_type(8))) short bf16x8;
typedef __attribute__((ext_vector_type(4))) short bf16x4;
typedef __attribute__((ext_vector_type(4))) float f32x4;

__device__ inline unsigned short f2bf(float f) {
  unsigned u = __float_as_uint(f);
  u += 0x7fff + ((u >> 16) & 1);   // RNE
  return (unsigned short)(u >> 16);
}
__device__ inline float bf2f(unsigned short h) {
  return __uint_as_float(((unsigned)h) << 16);
}

__device__ inline void gld_lds16(const void* g, void* l) {
  __builtin_amdgcn_global_load_lds(
      (const __attribute__((address_space(1))) void*)g,
      (__attribute__((address_space(3))) void*)l, 16, 0, 0);
}

__device__ inline bf16x8 ld_b64x2(const unsigned short* p) {
  union { bf16x8 v; bf16x4 h[2]; } u;
  u.h[0] = *(const bf16x4*)p;
  u.h[1] = *(const bf16x4*)(p + 4);
  return u.v;
}

// ---------------- fp32 -> bf16 convert (X + 3 weights, one launch) ------------
constexpr int NX4 = MROWS * H / 4;   // 2359296 float4s
constexpr int NW4 = H * H / 4;       // 147456 float4s
__global__ void convert_all(const float* __restrict__ X,
                            const float* __restrict__ Wq,
                            const float* __restrict__ Wk,
                            const float* __restrict__ Wv,
                            unsigned short* __restrict__ Xb,
                            unsigned short* __restrict__ Wb) {
  int i = blockIdx.x * blockDim.x + threadIdx.x;
  const int stride = gridDim.x * blockDim.x;
  const int total = NX4 + 3 * NW4;
  for (; i < total; i += stride) {
    const float* src;
    unsigned short* dst;
    int off;
    if (i < NX4) {
      src = X; dst = Xb; off = i;
    } else {
      int k = i - NX4;
      int w = k / NW4;
      off = k - w * NW4;
      src = (w == 0) ? Wq : (w == 1) ? Wk : Wv;
      dst = Wb + (size_t)w * H * H;
    }
    float4 v = ((const float4*)src)[off];
    ushort4 o;
    o.x = f2bf(v.x); o.y = f2bf(v.y); o.z = f2bf(v.z); o.w = f2bf(v.w);
    ((ushort4*)dst)[off] = o;
  }
}

// ---------------- QKV projection GEMM: Y = X * W^T + bias ----------------
// (r0 structure, proven 55 us / MfmaUtil ~30%. 128x128 tile, BK=64, 4 waves.
//  256-sq phase-interleave attempts regressed at this shape: K=768 gives only
//  12 K-tiles and 128KB LDS forces 1 block/CU -> pipeline never fills; the
//  implicit inter-block overlap of this 2.25-block/CU structure wins here.)
__launch_bounds__(256, 4)
__global__ void qkv_gemm(const unsigned short* __restrict__ Xb,
                         const unsigned short* __restrict__ Wb,
                         const float* __restrict__ bq, const float* __restrict__ bk,
                         const float* __restrict__ bv,
                         unsigned short* __restrict__ Qb, unsigned short* __restrict__ Kb,
                         unsigned short* __restrict__ Vb,
                         float* __restrict__ part,
                         float* __restrict__ out) {
  const int z = blockIdx.z;
  if (z == 0 && (blockIdx.x % 6) == 5) return;  // Q tail rows never consumed
  const unsigned short* W = Wb + (size_t)z * H * H;
  const float* bias = (z == 0) ? bq : (z == 1) ? bk : bv;
  unsigned short* Y = (z == 0) ? Qb : (z == 1) ? Kb : Vb;

  const int i0 = blockIdx.x * 128;
  const int j0 = blockIdx.y * 128;
  const int tid = threadIdx.x;
  const int wave = tid >> 6, lane = tid & 63;
  const int wr = wave >> 1, wc = wave & 1;
  const int col = lane & 15, quad = lane >> 4;

  // row stride 64 elems (8 chunks of 8 bf16); chunk swizzle ^(row&7)
  __shared__ unsigned short As[128 * 64];
  __shared__ unsigned short Bs[128 * 64];

  f32x4 acc[4][4];
#pragma unroll
  for (int i = 0; i < 4; i++)
#pragma unroll
    for (int j = 0; j < 4; j++) acc[i][j] = (f32x4){0.f, 0.f, 0.f, 0.f};

  int rS[4], gcS[4];
#pragma unroll
  for (int i = 0; i < 4; i++) {
    int s = tid + 256 * i;
    rS[i] = s >> 3;
    gcS[i] = (s & 7) ^ (rS[i] & 7);
  }

  for (int kt = 0; kt < 12; kt++) {
    const int k0 = kt * 64;
#pragma unroll
    for (int i = 0; i < 4; i++)
      gld_lds16(Xb + (size_t)(i0 + rS[i]) * H + k0 + gcS[i] * 8, &As[(tid + 256 * i) * 8]);
#pragma unroll
    for (int i = 0; i < 4; i++)
      gld_lds16(W + (size_t)(j0 + rS[i]) * H + k0 + gcS[i] * 8, &Bs[(tid + 256 * i) * 8]);
    __builtin_amdgcn_s_waitcnt(0);
    __syncthreads();

#pragma unroll
    for (int h = 0; h < 2; h++) {
      bf16x8 a[4], b[4];
#pragma unroll
      for (int mt = 0; mt < 4; mt++) {
        int r = wr * 64 + mt * 16 + col;
        a[mt] = *(const bf16x8*)&As[r * 64 + (((h * 4 + quad) ^ (r & 7)) * 8)];
      }
#pragma unroll
      for (int nt = 0; nt < 4; nt++) {
        int r = wc * 64 + nt * 16 + col;
        b[nt] = *(const bf16x8*)&Bs[r * 64 + (((h * 4 + quad) ^ (r & 7)) * 8)];
      }
#pragma unroll
      for (int mt = 0; mt < 4; mt++)
#pragma unroll
        for (int nt = 0; nt < 4; nt++)
          acc[mt][nt] = __builtin_amdgcn_mfma_f32_16x16x32_bf16(a[mt], b[nt], acc[mt][nt], 0, 0, 0);
    }
    __syncthreads();
  }

  float colsum[4] = {0.f, 0.f, 0.f, 0.f};
#pragma unroll
  for (int mt = 0; mt < 4; mt++) {
#pragma unroll
    for (int nt = 0; nt < 4; nt++) {
      const int j = j0 + wc * 64 + nt * 16 + col;
      const float bj = bias[j];
#pragma unroll
      for (int r = 0; r < 4; r++) {
        const int i = i0 + wr * 64 + mt * 16 + quad * 4 + r;
        const float v = acc[mt][nt][r] + bj;
        Y[(size_t)i * H + j] = f2bf(v);
        if (z == 2) {
          colsum[nt] += v;
          int s = i - (i / S) * S;
          if (s >= SQ) out[(size_t)i * H + j] = v;  // tail rows: out = V row
        }
      }
    }
  }
  if (z == 2) {
    const int b = blockIdx.x / 6;
#pragma unroll
    for (int nt = 0; nt < 4; nt++) {
      float s = colsum[nt];
      s += __shfl_xor(s, 16, 64);
      s += __shfl_xor(s, 32, 64);
      if (quad == 0) {
        const int j = j0 + wc * 64 + nt * 16 + col;
        atomicAdd(&part[b * H + j], s);
      }
    }
  }
}

// ---------------- fused masked attention ----------------
// One block per (b, h, chunk c). 192 live keys = chunk(64) + tail(128).
// Masked keys have score exactly 0 (multiplicative mask), closed form:
//   m = max(0, max live s);  Z = sum live e^(s-m) + 576 e^-m
//   ctx = (sum live e^(s-m) v + e^-m (Vtot - sum staged v)) / Z
// r5 changes vs r0:
//  (a) T14 async-V: V int4 loads issued BEFORE QK^T (regs), LDS transpose-
//      write deferred to after the post-softmax barrier. Counted gate
//      vmcnt(6) + raw s_barrier retires the 8 Q/K global_load_lds while the
//      6 V loads stay in flight under QK^T+softmax. Per-wave counting only
//      (each wave waits its own 14 vm-ops; no cross-wave count dependency).
//  (b) colsum-via-MFMA: staged-V column sums accumulated as
//      osum = mfma(ones, bvv, osum) inside the PV loop (B-frags reused);
//      every acc row equals the column sum, so vcorr = part - osum per lane.
//      Removes the 48x ds_read_u16 colsum pass, the red/vcorr LDS, and one
//      barrier.
__launch_bounds__(256, 2)
__global__ void attn_kernel(const unsigned short* __restrict__ Qb,
                            const unsigned short* __restrict__ Kb,
                            const unsigned short* __restrict__ Vb,
                            const float* __restrict__ part,
                            float* __restrict__ out) {
  const int bid = blockIdx.x;
  const int c = bid % CDD;
  const int h = (bid / CDD) % NH;
  const int b = bid / (CDD * NH);
  const int tid = threadIdx.x;
  const int wave = tid >> 6, lane = tid & 63;
  const int col = lane & 15, quad = lane >> 4;

  __shared__ __align__(16) char smem[57856];
  unsigned short* Qs = (unsigned short*)smem;            // 64x64 (stride 64, swizzled), 8KB
  unsigned short* Ks = (unsigned short*)(smem + 8192);   // 192x64 (stride 64, swizzled), 24KB
  unsigned short* Ps = (unsigned short*)smem;            // 64 x stride196 bf16 (aliases Qs+Ks)
  unsigned short* Vt = (unsigned short*)(smem + 32768);  // 64 x stride196 (V transposed)

  const size_t rowQ0 = (size_t)(b * S + c * 64) * H + h * DH;

  // --- stage Q (512 slots), K (1536 slots) via global_load_lds, swizzle ^(row&7)
  {
    int s0 = tid, s1 = tid + 256;
    int r0 = s0 >> 3, g0 = (s0 & 7) ^ (r0 & 7);
    int r1 = s1 >> 3, g1 = (s1 & 7) ^ (r1 & 7);
    gld_lds16(Qb + rowQ0 + (size_t)r0 * H + g0 * 8, &Qs[s0 * 8]);
    gld_lds16(Qb + rowQ0 + (size_t)r1 * H + g1 * 8, &Qs[s1 * 8]);
  }
#pragma unroll
  for (int j = 0; j < 6; j++) {
    int s = tid + 256 * j;
    int key = s >> 3;
    int gkey = (key < 64) ? (c * 64 + key) : (576 + key);
    int gc = (s & 7) ^ (key & 7);
    gld_lds16(Kb + (size_t)(b * S + gkey) * H + h * DH + gc * 8, &Ks[s * 8]);
  }
  asm volatile("" ::: "memory");  // pin issue order: Q/K (8 vm-ops) before V (6)

  // --- T14: issue V loads now (regs); LDS write deferred past QK^T/softmax
  int4 uv[6];
#pragma unroll
  for (int j = 0; j < 6; j++) {
    int s = tid + 256 * j;
    int key = s >> 3;
    int f0 = (s & 7) * 8;
    int gkey = (key < 64) ? (c * 64 + key) : (576 + key);
    uv[j] = *(const int4*)(Vb + (size_t)(b * S + gkey) * H + h * DH + f0);
  }
  // counted gate: retire the 8 Q/K stages; keep the 6 V loads in flight.
  asm volatile("s_waitcnt vmcnt(6)" ::: "memory");
  __builtin_amdgcn_sched_barrier(0);
  __builtin_amdgcn_s_barrier();
  __builtin_amdgcn_sched_barrier(0);

  // --- QK^T: wave handles q-rows [wave*16, wave*16+16), 12 col-tiles, K=64
  f32x4 sc[12];
#pragma unroll
  for (int n = 0; n < 12; n++) sc[n] = (f32x4){0.f, 0.f, 0.f, 0.f};
  {
    const int rq = wave * 16 + col;
    bf16x8 a0 = *(const bf16x8*)&Qs[rq * 64 + ((quad ^ (rq & 7)) * 8)];
    bf16x8 a1 = *(const bf16x8*)&Qs[rq * 64 + (((4 + quad) ^ (rq & 7)) * 8)];
#pragma unroll
    for (int n = 0; n < 12; n++) {
      const int rk = n * 16 + col;
      bf16x8 b0 = *(const bf16x8*)&Ks[rk * 64 + ((quad ^ (rk & 7)) * 8)];
      bf16x8 b1 = *(const bf16x8*)&Ks[rk * 64 + (((4 + quad) ^ (rk & 7)) * 8)];
      sc[n] = __builtin_amdgcn_mfma_f32_16x16x32_bf16(a0, b0, sc[n], 0, 0, 0);
      sc[n] = __builtin_amdgcn_mfma_f32_16x16x32_bf16(a1, b1, sc[n], 0, 0, 0);
    }
  }

  // --- masked softmax (exact, multiplicative-mask semantics)
  float em[4], zin[4];
  {
    const float scale = 0.125f;  // 1/sqrt(64)
#pragma unroll
    for (int r = 0; r < 4; r++) {
      float mx = sc[0][r];
#pragma unroll
      for (int n = 1; n < 12; n++) mx = fmaxf(mx, sc[n][r]);
#pragma unroll
      for (int msk = 1; msk <= 8; msk <<= 1) mx = fmaxf(mx, __shfl_xor(mx, msk, 64));
      const float mrow = fmaxf(mx * scale, 0.f);
      float rs = 0.f;
#pragma unroll
      for (int n = 0; n < 12; n++) {
        float p = __expf(sc[n][r] * scale - mrow);
        sc[n][r] = p;
        rs += p;
      }
#pragma unroll
      for (int msk = 1; msk <= 8; msk <<= 1) rs += __shfl_xor(rs, msk, 64);
      const float e = __expf(-mrow);
      em[r] = e;
      zin[r] = 1.f / (rs + 576.f * e);
    }
  }
  // all waves' Qs/Ks reads done -> Ps (aliased) writes safe. This sync also
  // drains the V loads (vmcnt 0) exactly where the transpose-writes need uv.
  __syncthreads();

  // --- P -> LDS (bf16, stride 196)
#pragma unroll
  for (int n = 0; n < 12; n++)
#pragma unroll
    for (int r = 0; r < 4; r++)
      Ps[(wave * 16 + quad * 4 + r) * 196 + n * 16 + col] = f2bf(sc[n][r]);

  // --- V transpose-write from regs: Vt[d][key], stride 196
#pragma unroll
  for (int j = 0; j < 6; j++) {
    int s = tid + 256 * j;
    int key = s >> 3;
    int f0 = (s & 7) * 8;
    union { int4 i4; unsigned short u[8]; } w;
    w.i4 = uv[j];
#pragma unroll
    for (int i = 0; i < 8; i++) Vt[(f0 + i) * 196 + key] = w.u[i];
  }
  __syncthreads();

  // --- PV (+ staged-V column sums via ones-MFMA): rows [wave*16,+16) x 64 cols
  f32x4 o[4], osum[4];
#pragma unroll
  for (int n2 = 0; n2 < 4; n2++) {
    o[n2] = (f32x4){0.f, 0.f, 0.f, 0.f};
    osum[n2] = (f32x4){0.f, 0.f, 0.f, 0.f};
  }
  bf16x8 ones;
#pragma unroll
  for (int i = 0; i < 8; i++) ones[i] = (short)0x3F80;  // bf16 1.0
#pragma unroll
  for (int ks = 0; ks < 6; ks++) {
    bf16x8 a = ld_b64x2(&Ps[(wave * 16 + col) * 196 + ks * 32 + quad * 8]);
#pragma unroll
    for (int n2 = 0; n2 < 4; n2++) {
      bf16x8 bvv = ld_b64x2(&Vt[(n2 * 16 + col) * 196 + ks * 32 + quad * 8]);
      o[n2] = __builtin_amdgcn_mfma_f32_16x16x32_bf16(a, bvv, o[n2], 0, 0, 0);
      osum[n2] = __builtin_amdgcn_mfma_f32_16x16x32_bf16(ones, bvv, osum[n2], 0, 0, 0);
    }
  }

  // --- epilogue: masked-V correction (vcorr = Vtot - staged sum), normalize
#pragma unroll
  for (int n2 = 0; n2 < 4; n2++) {
    const int d = n2 * 16 + col;
    const float vc = part[b * H + h * DH + d] - osum[n2][0];
#pragma unroll
    for (int r = 0; r < 4; r++) {
      const int m = wave * 16 + quad * 4 + r;
      const float val = (o[n2][r] + em[r] * vc) * zin[r];
      out[(size_t)(b * S + c * 64 + m) * H + h * DH + d] = val;
    }
  }
}

extern "C" void kernel_launch(void* const* d_in, const int* in_sizes, int n_in,
                              void* d_out, int out_size, void* d_ws, size_t ws_size,
                              hipStream_t stream) {
  const float* X  = (const float*)d_in[0];
  const float* Wq = (const float*)d_in[1];
  const float* bq = (const float*)d_in[2];
  const float* Wk = (const float*)d_in[3];
  const float* bk = (const float*)d_in[4];
  const float* Wv = (const float*)d_in[5];
  const float* bv = (const float*)d_in[6];
  float* out = (float*)d_out;

  char* ws = (char*)d_ws;
  // workspace layout (~75.5 MB total)
  unsigned short* Xb   = (unsigned short*)ws;                    // 12288x768 bf16
  unsigned short* Wb   = (unsigned short*)(ws + 18874368);       // 3x768x768 bf16
  unsigned short* Qb   = (unsigned short*)(ws + 22413312);       // 12288x768 bf16
  unsigned short* Kb   = (unsigned short*)(ws + 41287680);
  unsigned short* Vb   = (unsigned short*)(ws + 60162048);
  float*          part = (float*)(ws + 79036416);                // 16x768 f32 (atomic)

  hipMemsetAsync(part, 0, Bb * H * sizeof(float), stream);
  convert_all<<<2048, 256, 0, stream>>>(X, Wq, Wk, Wv, Xb, Wb);
  qkv_gemm<<<dim3(96, 6, 3), 256, 0, stream>>>(Xb, Wb, bq, bk, bv, Qb, Kb, Vb, part, out);
  attn_kernel<<<1920, 256, 0, stream>>>(Qb, Kb, Vb, part, out);
}